// Round 6
// baseline (54.992 us; speedup 1.0000x reference)
//
#include <hip/hip_runtime.h>
#include <hip/hip_bf16.h>

// SINDy: theta(N,969) @ (C*mask)(969,16), plus l1 = mean|C*mask|.
// N=262144, latent=16, lib = 1 + 16 + 136 + 816 = 969; K padded to 992 = 31*32.
//
// R5 design — no LDS: rotation i -> i+4 (mod 16) on latent indices makes the
// library rotation-closed; lane l (slice g=l>>4) computes the g-th orbit
// member of each of 248 orbit reps as compile-time-indexed products of its
// ROTATED z. Coefficients are gathered to match by the prep kernel.
// Each wave = one 16x16 out tile, 31 MFMAs, zero LDS traffic.
//
// R6 change: fp32->bf16 via 3-op round-half-up pack (2x v_add_u32 + v_perm_b32)
// instead of the ~9-op header cast — the cast was ~77% of all VALU work.

#define LIB    969
#define NSLOT  248
#define NCHUNK 31
#define NROWS  262144
#define NOUT   16

typedef __attribute__((ext_vector_type(8))) short bf16x8;
typedef __attribute__((ext_vector_type(4))) float f32x4;

struct Maps {
  unsigned char a[NSLOT], b[NSLOT], c[NSLOT];  // zrot indices (16 = sentinel 1.0)
  short l[NSLOT][4];                           // library row per slice g, or -1
};

constexpr Maps build_maps() {
  Maps M{};
  int n = 0;
  // const term: product 1 in every slice; coeff only at g=0
  M.a[n] = 16; M.b[n] = 16; M.c[n] = 16;
  M.l[n][0] = 0; M.l[n][1] = -1; M.l[n][2] = -1; M.l[n][3] = -1; n++;
  // linear orbits: reps a0 = 0..3, member g = z_{(a0+4g)&15}
  for (int a0 = 0; a0 < 4; a0++) {
    M.a[n] = (unsigned char)a0; M.b[n] = 16; M.c[n] = 16;
    for (int g = 0; g < 4; g++) M.l[n][g] = (short)(1 + ((a0 + 4 * g) & 15));
    n++;
  }
  // pair orbits
  bool pv[16][16] = {};
  for (int i = 0; i < 16; i++)
    for (int j = i; j < 16; j++) {
      if (pv[i][j]) continue;
      M.a[n] = (unsigned char)i; M.b[n] = (unsigned char)j; M.c[n] = 16;
      int mi[4], mj[4];
      for (int g = 0; g < 4; g++) {
        int x = (i + 4 * g) & 15, y = (j + 4 * g) & 15;
        int lo = x < y ? x : y, hi = x < y ? y : x;
        mi[g] = lo; mj[g] = hi; pv[lo][hi] = true;
      }
      for (int g = 0; g < 4; g++) {
        bool dup = false;
        for (int h = 0; h < g; h++) if (mi[h] == mi[g] && mj[h] == mj[g]) dup = true;
        M.l[n][g] = dup ? (short)-1
                        : (short)(17 + mi[g] * 16 - mi[g] * (mi[g] - 1) / 2 + (mj[g] - mi[g]));
      }
      n++;
    }
  // triple orbits (all size 4)
  bool tv[16][16][16] = {};
  for (int i = 0; i < 16; i++)
    for (int j = i; j < 16; j++)
      for (int k = j; k < 16; k++) {
        if (tv[i][j][k]) continue;
        M.a[n] = (unsigned char)i; M.b[n] = (unsigned char)j; M.c[n] = (unsigned char)k;
        int ti[4], tj[4], tk[4];
        for (int g = 0; g < 4; g++) {
          int x = (i + 4 * g) & 15, y = (j + 4 * g) & 15, w = (k + 4 * g) & 15, t;
          if (x > y) { t = x; x = y; y = t; }
          if (y > w) { t = y; y = w; w = t; }
          if (x > y) { t = x; x = y; y = t; }
          ti[g] = x; tj[g] = y; tk[g] = w; tv[x][y][w] = true;
        }
        for (int g = 0; g < 4; g++) {
          bool dup = false;
          for (int h = 0; h < g; h++)
            if (ti[h] == ti[g] && tj[h] == tj[g] && tk[h] == tk[g]) dup = true;
          if (dup) { M.l[n][g] = -1; continue; }
          int i2 = ti[g], j2 = tj[g], k2 = tk[g];
          int base = 0;
          for (int a2 = 0; a2 < i2; a2++) base += (16 - a2) * (17 - a2) / 2;
          int off = (j2 - i2) * (16 - i2) - (j2 - i2) * (j2 - i2 - 1) / 2 + (k2 - j2);
          M.l[n][g] = (short)(153 + base + off);
        }
        n++;
      }
  // pad to 248 slots (product 1, coeff 0 everywhere)
  for (; n < NSLOT; n++) {
    M.a[n] = 16; M.b[n] = 16; M.c[n] = 16;
    M.l[n][0] = M.l[n][1] = M.l[n][2] = M.l[n][3] = -1;
  }
  return M;
}
constexpr Maps MP = build_maps();

// ---- prep: gather masked coeffs (bf16 RNE) into B-frag/slot order; L1 sum ----
__device__ inline unsigned short f2bf(float x) {
  unsigned int u = __builtin_bit_cast(unsigned int, x);
  u += 0x7fffu + ((u >> 16) & 1u);
  return (unsigned short)(u >> 16);
}
__global__ __launch_bounds__(256) void prep_kernel(const float* __restrict__ C,
                                                   const float* __restrict__ M,
                                                   unsigned short* __restrict__ Cb,
                                                   float* __restrict__ acc) {
  const int idx = blockIdx.x * 256 + threadIdx.x;   // 0 .. 15871 = NSLOT*4*16
  const int s = idx >> 6, g = (idx >> 4) & 3, o = idx & 15;
  const int li = MP.l[s][g];
  float v = 0.f;
  if (li >= 0) v = C[li * 16 + o] * M[li * 16 + o];
  Cb[(((s >> 3) * 4 + g) * 16 + o) * 8 + (s & 7)] = f2bf(v);
  float t = fabsf(v);
  #pragma unroll
  for (int off = 32; off > 0; off >>= 1) t += __shfl_down(t, off);
  if ((threadIdx.x & 63) == 0) atomicAdd(acc, t);
}

// fp32 pair -> packed bf16x2, round-half-up: 2x v_add_u32 + 1x v_perm_b32.
// perm(a,b,s): result byte i = byte s_i of ((a << 32) | b); 0x07060302 picks
// hi16(b) into low half, hi16(a) into high half.
__device__ inline unsigned int pack_hi(float a, float b) {
  unsigned int ua = __builtin_bit_cast(unsigned int, a) + 0x8000u;
  unsigned int ub = __builtin_bit_cast(unsigned int, b) + 0x8000u;
  return __builtin_amdgcn_perm(ub, ua, 0x07060302u);
}

__global__ __launch_bounds__(256) void sindy_kernel(const float* __restrict__ z,
                                                    const unsigned short* __restrict__ Cb,
                                                    const float* __restrict__ acc,
                                                    float* __restrict__ out) {
  const int lane = threadIdx.x & 63;
  const int g = lane >> 4;                          // k-slice
  const int o = lane & 15;                          // row-in-tile (A) / out col (B)
  const int rowBase = blockIdx.x * 64 + (threadIdx.x >> 6) * 16;
  const int r = rowBase + o;

  // load z-row r (each row read by 4 lanes; L1-served)
  float z17[17];
  {
    const float4* z4 = (const float4*)z;
    #pragma unroll
    for (int c4 = 0; c4 < 4; c4++) {
      float4 v = z4[r * 4 + c4];
      z17[c4 * 4 + 0] = v.x; z17[c4 * 4 + 1] = v.y;
      z17[c4 * 4 + 2] = v.z; z17[c4 * 4 + 3] = v.w;
    }
    z17[16] = 1.0f;
  }
  // rotate by 4g with two compile-time-indexed cndmask layers
  const bool b0 = (g & 1) != 0, b1 = (g & 2) != 0;
  float t16[16], zr[17];
  #pragma unroll
  for (int m = 0; m < 16; m++) t16[m] = b0 ? z17[(m + 4) & 15] : z17[m];
  #pragma unroll
  for (int m = 0; m < 16; m++) zr[m] = b1 ? t16[(m + 8) & 15] : t16[m];
  zr[16] = 1.0f;

  f32x4 acc4 = {0.f, 0.f, 0.f, 0.f};
  #pragma unroll
  for (int c = 0; c < NCHUNK; c++) {
    float th[8];
    #pragma unroll
    for (int m = 0; m < 8; m++) {
      const int s = c * 8 + m;
      th[m] = (zr[MP.a[s]] * zr[MP.b[s]]) * zr[MP.c[s]];
    }
    uint4 pk;
    pk.x = pack_hi(th[0], th[1]);
    pk.y = pack_hi(th[2], th[3]);
    pk.z = pack_hi(th[4], th[5]);
    pk.w = pack_hi(th[6], th[7]);
    bf16x8 af = __builtin_bit_cast(bf16x8, pk);
    bf16x8 bfrag = *(const bf16x8*)(Cb + ((c * 4 + g) * 16 + o) * 8);
    acc4 = __builtin_amdgcn_mfma_f32_16x16x32_bf16(af, bfrag, acc4, 0, 0, 0);
  }

  // C/D layout (m89-verified): col = lane&15, row = 4*(lane>>4) + reg
  #pragma unroll
  for (int p = 0; p < 4; p++)
    out[(rowBase + 4 * g + p) * 16 + o] = acc4[p];

  if (blockIdx.x == 0 && threadIdx.x == 0)
    out[NROWS * NOUT] = acc[0] * (1.0f / 15504.0f);  // mean over 969*16
}

extern "C" void kernel_launch(void* const* d_in, const int* in_sizes, int n_in,
                              void* d_out, int out_size, void* d_ws, size_t ws_size,
                              hipStream_t stream) {
  const float* z = (const float*)d_in[0];
  const float* C = (const float*)d_in[1];
  const float* M = (const float*)d_in[2];
  float* out = (float*)d_out;
  float* acc = (float*)d_ws;                          // [0]: L1 accumulator
  unsigned short* Cb = (unsigned short*)((char*)d_ws + 64); // 31744 B coeff slots

  (void)hipMemsetAsync(d_ws, 0, 4, stream);           // zero L1 accumulator
  prep_kernel<<<NSLOT * 4 * 16 / 256, 256, 0, stream>>>(C, M, Cb, acc);
  sindy_kernel<<<NROWS / 64, 256, 0, stream>>>(z, Cb, acc, out);
}